// Round 9
// baseline (130.139 us; speedup 1.0000x reference)
//
#include <hip/hip_runtime.h>
#include <hip/hip_bf16.h>

typedef __attribute__((ext_vector_type(8))) short short8_t;
typedef __attribute__((ext_vector_type(4))) short short4_t;
typedef __attribute__((ext_vector_type(4))) float float4_t;

#define B_   4
#define C_   256
#define N_   4096
#define DQK  32
#define LOG2E 1.4426950408889634f

#define LGKM0    asm volatile("s_waitcnt lgkmcnt(0)" ::: "memory")
#define SBAR     __builtin_amdgcn_s_barrier()
#define SCHEDB   __builtin_amdgcn_sched_barrier(0)

__device__ __forceinline__ unsigned short f2bf(float x) {
    union { float f; unsigned int u; } v; v.f = x;
    unsigned int r = v.u + 0x7FFFu + ((v.u >> 16) & 1u);   // RNE
    return (unsigned short)(r >> 16);
}
__device__ __forceinline__ unsigned short f2bf_hw(float x) {
    return __bfloat16_as_ushort(__float2bfloat16(x));      // hw RNE, pairs to cvt_pk
}

// ---------------- weight casts ----------------
__global__ __launch_bounds__(256) void cast_w_k(
        const float* __restrict__ Wq, const float* __restrict__ Wk,
        const float* __restrict__ Wv,
        unsigned short* __restrict__ Wqb, unsigned short* __restrict__ Wkb,
        unsigned short* __restrict__ Wvb) {
    int i = blockIdx.x * 256 + threadIdx.x;
    if (i < 8192)            Wqb[i] = f2bf(Wq[i]);
    else if (i < 16384)      Wkb[i - 8192] = f2bf(Wk[i - 8192]);
    else                     Wvb[i - 16384] = f2bf(Wv[i - 16384]);
}

// ---------------- pq / pk projection, reading x f32 [b][c][n] directly ----------------
__global__ __launch_bounds__(256) void proj_qk_k(
        const float* __restrict__ q_in, const float* __restrict__ k_in,
        const unsigned short* __restrict__ Wqb, const unsigned short* __restrict__ Wkb,
        const float* __restrict__ bq, const float* __restrict__ bk,
        unsigned short* __restrict__ pqT, unsigned short* __restrict__ pkT) {
    int b = blockIdx.y, z = blockIdx.z;
    const float* X = z ? k_in : q_in;
    const unsigned short* W = z ? Wkb : Wqb;
    const float* bias = z ? bk : bq;
    unsigned short* P = z ? pkT : pqT;
    float scl = z ? 1.0f : LOG2E;
    int tid = threadIdx.x, wave = tid >> 6, lane = tid & 63, l15 = lane & 15, g = lane >> 4;
    int nb = blockIdx.x * 64 + wave * 16;
    float4_t acc0 = {0.f, 0.f, 0.f, 0.f}, acc1 = {0.f, 0.f, 0.f, 0.f};
    const float* Xcol = X + (size_t)b * C_ * N_ + nb + l15;
#pragma unroll
    for (int kk = 0; kk < 8; ++kk) {
        short8_t a;
#pragma unroll
        for (int j = 0; j < 8; ++j)
            a[j] = (short)f2bf(Xcol[(size_t)(kk * 32 + 8 * g + j) * N_]);
        short8_t b0 = *(const short8_t*)(W + (size_t)l15 * C_ + kk * 32 + 8 * g);
        short8_t b1 = *(const short8_t*)(W + (size_t)(16 + l15) * C_ + kk * 32 + 8 * g);
        acc0 = __builtin_amdgcn_mfma_f32_16x16x32_bf16(a, b0, acc0, 0, 0, 0);
        acc1 = __builtin_amdgcn_mfma_f32_16x16x32_bf16(a, b1, acc1, 0, 0, 0);
    }
#pragma unroll
    for (int r = 0; r < 4; ++r) {
        int n = nb + 4 * g + r;
        P[((size_t)b * N_ + n) * DQK + l15]      = f2bf((acc0[r] + bias[l15]) * scl);
        P[((size_t)b * N_ + n) * DQK + 16 + l15] = f2bf((acc1[r] + bias[16 + l15]) * scl);
    }
}

// ---------------- pv projection: pv[b][c][m'] = Wv x v + bv, keys pi-permuted ----------------
__global__ __launch_bounds__(256) void proj_v_k(
        const float* __restrict__ v_in, const unsigned short* __restrict__ Wvb,
        const float* __restrict__ bv, unsigned short* __restrict__ pv) {
    int b = blockIdx.y;
    int tid = threadIdx.x, wave = tid >> 6, lane = tid & 63, l15 = lane & 15, g = lane >> 4;
    int mb = blockIdx.x * 16;
    int m = mb + l15;
    int k32 = m & 31;
    int pcol = (k32 < 16) ? ((k32 >> 2) * 8 + (k32 & 3))
                          : (((k32 - 16) >> 2) * 8 + 4 + (k32 & 3));
    int mcol = (m & ~31) + pcol;
    float4_t acc[4];
#pragma unroll
    for (int i = 0; i < 4; ++i) acc[i] = (float4_t){0.f, 0.f, 0.f, 0.f};
    const float* Vcol = v_in + (size_t)b * C_ * N_ + mb + l15;
#pragma unroll
    for (int kk = 0; kk < 8; ++kk) {
        short8_t bf;
#pragma unroll
        for (int j = 0; j < 8; ++j)
            bf[j] = (short)f2bf(Vcol[(size_t)(kk * 32 + 8 * g + j) * N_]);
#pragma unroll
        for (int ct = 0; ct < 4; ++ct) {
            short8_t af = *(const short8_t*)(Wvb + (size_t)(wave * 64 + ct * 16 + l15) * C_ + kk * 32 + 8 * g);
            acc[ct] = __builtin_amdgcn_mfma_f32_16x16x32_bf16(af, bf, acc[ct], 0, 0, 0);
        }
    }
#pragma unroll
    for (int ct = 0; ct < 4; ++ct)
#pragma unroll
        for (int r = 0; r < 4; ++r) {
            int c = wave * 64 + ct * 16 + 4 * g + r;
            pv[((size_t)b * C_ + c) * N_ + mcol] = f2bf(acc[ct][r] + bv[c]);
        }
}

// ---------------- flash attention: V in registers, only P through LDS ----------------
// Wave w: produces QK for q-slice w (16q), consumes PV for channels [64w,64w+64)
// x all 64q (acc[4ct][4qt]). V fragments global->reg, double-buffered, read ONCE
// per block (no LDS V). P(t+1) computed during tile t (r8 pipeline), shared via
// 2x8KB LDS ping-pong. One barrier + one lgkmcnt drain per tile; no vmcnt drains
// (register loads are compiler-tracked).
__global__ __launch_bounds__(256, 2) void attn_split_k(
        const unsigned short* __restrict__ pqT, const unsigned short* __restrict__ pkT,
        const unsigned short* __restrict__ pv,
        float* __restrict__ accP, float* __restrict__ lP, int KS) {
    __shared__ __align__(16) short8_t Pl[2][4][2][4][16];   // 16KB: [buf][qt][kh][g][l15]
    // XCD-chunked bijective swizzle: each XCD covers all 64 qb of one (s,b)
    int nqb = gridDim.x;
    int lin = blockIdx.x + nqb * (blockIdx.y + KS * blockIdx.z);
    int cpx = (nqb * KS * 4) >> 3;
    int sl  = (lin & 7) * cpx + (lin >> 3);
    int qbi = sl % nqb;
    int s   = (sl / nqb) % KS;
    int b   = sl / (nqb * KS);

    int kps = N_ / KS, ks0 = s * kps, nt = kps >> 6;
    int tid = threadIdx.x, wave = tid >> 6, lane = tid & 63, l15 = lane & 15, g = lane >> 4;
    int qb = qbi * 64;

    short8_t qf = *(const short8_t*)(pqT + ((size_t)b * N_ + qb + wave * 16 + l15) * DQK + 8 * g);
    float4_t acc[4][4];   // [ct][qt]
#pragma unroll
    for (int i = 0; i < 4; ++i)
#pragma unroll
        for (int j = 0; j < 4; ++j) acc[i][j] = (float4_t){0.f, 0.f, 0.f, 0.f};
    float4_t accl = {0.f, 0.f, 0.f, 0.f};
    short8_t onef;
#pragma unroll
    for (int j = 0; j < 8; ++j) onef[j] = (short)0x3F80;    // bf16 1.0
    const float4_t zero4 = {0.f, 0.f, 0.f, 0.f};
    const char* pvb8 = (const char*)(pv + (size_t)b * C_ * N_);
    const char* pkTb = (const char*)pkT + (size_t)b * N_ * DQK * 2;

    // persistent byte offsets
    unsigned voff[4][2];
#pragma unroll
    for (int ct = 0; ct < 4; ++ct)
#pragma unroll
        for (int kh = 0; kh < 2; ++kh)
            voff[ct][kh] = (unsigned)((((wave * 64 + ct * 16 + l15) * N_) + ks0 + kh * 32 + 8 * g) * 2);
    unsigned koff = (unsigned)(((ks0 + l15) * DQK + 8 * g) * 2);

#define VLOAD(DST)                                                            \
    _Pragma("unroll")                                                         \
    for (int ct_ = 0; ct_ < 4; ++ct_)                                         \
        _Pragma("unroll")                                                     \
        for (int kh_ = 0; kh_ < 2; ++kh_) {                                   \
            DST[ct_][kh_] = *(const short8_t*)(pvb8 + voff[ct_][kh_]);        \
            voff[ct_][kh_] += 128;                                            \
        }

#define KFLOAD(DST)                                                           \
    _Pragma("unroll")                                                         \
    for (int it_ = 0; it_ < 4; ++it_)                                         \
        DST[it_] = *(const short8_t*)(pkTb + koff + it_ * 1024);              \
    koff += 4096;

// QK(t+1) -> exp -> pack -> accl -> ds_write to Pl[NB]
#define QKWR(KF, NB)                                                          \
    {                                                                          \
        float4_t sv_[4];                                                       \
        _Pragma("unroll")                                                      \
        for (int it_ = 0; it_ < 4; ++it_)                                      \
            sv_[it_] = __builtin_amdgcn_mfma_f32_16x16x32_bf16(KF[it_], qf, zero4, 0, 0, 0); \
        float p_[16];                                                          \
        _Pragma("unroll")                                                      \
        for (int it_ = 0; it_ < 4; ++it_)                                      \
            _Pragma("unroll")                                                  \
            for (int r_ = 0; r_ < 4; ++r_)                                     \
                p_[it_ * 4 + r_] = exp2f(sv_[it_][r_]);                        \
        short8_t pbn0_, pbn1_;                                                 \
        _Pragma("unroll")                                                      \
        for (int j_ = 0; j_ < 4; ++j_) {                                       \
            pbn0_[j_]     = (short)f2bf_hw(p_[j_]);                            \
            pbn0_[4 + j_] = (short)f2bf_hw(p_[4 + j_]);                        \
            pbn1_[j_]     = (short)f2bf_hw(p_[8 + j_]);                        \
            pbn1_[4 + j_] = (short)f2bf_hw(p_[12 + j_]);                       \
        }                                                                      \
        accl = __builtin_amdgcn_mfma_f32_16x16x32_bf16(onef, pbn0_, accl, 0, 0, 0); \
        accl = __builtin_amdgcn_mfma_f32_16x16x32_bf16(onef, pbn1_, accl, 0, 0, 0); \
        Pl[NB][wave][0][g][l15] = pbn0_;                                       \
        Pl[NB][wave][1][g][l15] = pbn1_;                                       \
    }

#define PFREAD(DST, CB, QT0)                                                  \
    _Pragma("unroll")                                                         \
    for (int q2_ = 0; q2_ < 2; ++q2_)                                         \
        _Pragma("unroll")                                                     \
        for (int kh_ = 0; kh_ < 2; ++kh_)                                     \
            DST[q2_][kh_] = Pl[CB][(QT0) + q2_][kh_][g][l15];

#define PVM(VS, PF, QT0)                                                      \
    _Pragma("unroll")                                                         \
    for (int ct_ = 0; ct_ < 4; ++ct_)                                         \
        _Pragma("unroll")                                                     \
        for (int q2_ = 0; q2_ < 2; ++q2_) {                                   \
            acc[ct_][(QT0) + q2_] = __builtin_amdgcn_mfma_f32_16x16x32_bf16(VS[ct_][0], PF[q2_][0], acc[ct_][(QT0) + q2_], 0, 0, 0); \
            acc[ct_][(QT0) + q2_] = __builtin_amdgcn_mfma_f32_16x16x32_bf16(VS[ct_][1], PF[q2_][1], acc[ct_][(QT0) + q2_], 0, 0, 0); \
        }

// body for tile T: read P(T) frags; produce P(T+1); PV(T) from register V; refill V.
#define BODY(T, VS, KF, CB, NB)                                               \
    {                                                                          \
        short8_t pfA_[2][2], pfB_[2][2];                                       \
        PFREAD(pfA_, CB, 0)                                                    \
        if ((T) + 1 < nt) { QKWR(KF, NB) }                                     \
        KFLOAD(KF)                                                             \
        PFREAD(pfB_, CB, 2)                                                    \
        __builtin_amdgcn_s_setprio(1);                                         \
        PVM(VS, pfA_, 0)                                                       \
        PVM(VS, pfB_, 2)                                                       \
        __builtin_amdgcn_s_setprio(0);                                         \
        VLOAD(VS)                                                              \
        LGKM0; SCHEDB;                                                         \
        SBAR;                                                                  \
    }

    // ---- prologue ----
    short8_t vX[4][2], vY[4][2], kfA[4], kfB[4];
    VLOAD(vX)            // V(0)
    KFLOAD(kfA)          // kf(0)
    VLOAD(vY)            // V(1)
    KFLOAD(kfB)          // kf(1)
    QKWR(kfA, 0)         // P(0) -> buf0, accl(0)
    KFLOAD(kfA)          // kf(2)
    LGKM0; SCHEDB;
    SBAR;

    for (int t = 0; t < nt; t += 2) {
        BODY(t,     vX, kfB, 0, 1)
        BODY(t + 1, vY, kfA, 1, 0)
    }

    // ---- epilogue: partial acc + l ----
    if (g == 0)
        lP[(size_t)(b * KS + s) * N_ + qb + wave * 16 + l15] = accl[0];
    float* accOut = accP + ((size_t)(b * KS + s) * C_) * N_;
#pragma unroll
    for (int ct = 0; ct < 4; ++ct)
#pragma unroll
        for (int qt = 0; qt < 4; ++qt)
#pragma unroll
            for (int r = 0; r < 4; ++r) {
                int c = wave * 64 + ct * 16 + 4 * g + r;
                accOut[(size_t)c * N_ + qb + qt * 16 + l15] = acc[ct][qt][r];
            }
#undef VLOAD
#undef KFLOAD
#undef QKWR
#undef PFREAD
#undef PVM
#undef BODY
}

// ---------------- combine splits + normalize + gamma*out + v ----------------
__global__ __launch_bounds__(256) void combine_k(
        const float* __restrict__ accP, const float* __restrict__ lP,
        const float* __restrict__ v_in, const float* __restrict__ gamma,
        float* __restrict__ out, int KS) {
    int i = blockIdx.x * 256 + threadIdx.x;
    const int nq4 = N_ / 4;
    int q0 = (i % nq4) * 4;
    int c  = (i / nq4) % C_;
    int b  = i / (nq4 * C_);
    float4_t num = {0.f, 0.f, 0.f, 0.f}, den = {0.f, 0.f, 0.f, 0.f};
    for (int s = 0; s < KS; ++s) {
        float4_t l4 = *(const float4_t*)(lP + (size_t)(b * KS + s) * N_ + q0);
        float4_t a4 = *(const float4_t*)(accP + ((size_t)(b * KS + s) * C_ + c) * N_ + q0);
#pragma unroll
        for (int j = 0; j < 4; ++j) {
            den[j] += l4[j];
            num[j] += a4[j];
        }
    }
    float gm = gamma[0];
    size_t idx = ((size_t)(b * C_ + c)) * N_ + q0;
    float4_t vi = *(const float4_t*)(v_in + idx);
    float4_t o;
#pragma unroll
    for (int j = 0; j < 4; ++j) o[j] = gm * num[j] / den[j] + vi[j];
    *(float4_t*)(out + idx) = o;
}

extern "C" void kernel_launch(void* const* d_in, const int* in_sizes, int n_in,
                              void* d_out, int out_size, void* d_ws, size_t ws_size,
                              hipStream_t stream) {
    (void)in_sizes; (void)n_in; (void)out_size;
    const float* v_in  = (const float*)d_in[0];
    const float* k_in  = (const float*)d_in[1];
    const float* q_in  = (const float*)d_in[2];
    const float* Wq    = (const float*)d_in[3];
    const float* bq    = (const float*)d_in[4];
    const float* Wk    = (const float*)d_in[5];
    const float* bk    = (const float*)d_in[6];
    const float* Wv    = (const float*)d_in[7];
    const float* bv    = (const float*)d_in[8];
    const float* gamma = (const float*)d_in[9];
    float* out = (float*)d_out;

    char* ws = (char*)d_ws;
    unsigned short* pvb = (unsigned short*)(ws + 0);          // 8.39 MB [b][c][m'] pi-permuted
    unsigned short* pqT = (unsigned short*)(ws + 8388608);    // 1 MB [b][n][32] (x log2e)
    unsigned short* pkT = (unsigned short*)(ws + 9437184);    // 1 MB + 24 KB pad (pipelined overread)
    unsigned short* Wqb = (unsigned short*)(ws + 10502144);   // 16 KB
    unsigned short* Wkb = (unsigned short*)(ws + 10518528);   // 16 KB
    unsigned short* Wvb = (unsigned short*)(ws + 10534912);   // 128 KB
    const size_t base2 = 10665984;

    int KS = 2;
    while (KS > 1) {
        size_t need = base2 + (size_t)KS * 16777216 + (size_t)KS * 262144;
        if (need <= ws_size) break;
        KS >>= 1;
    }
    float* accP = (float*)(ws + base2);                          // KS*16.78 MB [b][s][c][q]
    float* lP   = (float*)(ws + base2 + (size_t)KS * 16777216);  // KS*64 KB

    cast_w_k<<<320, 256, 0, stream>>>(Wq, Wk, Wv, Wqb, Wkb, Wvb);
    proj_qk_k<<<dim3(64, 4, 2), 256, 0, stream>>>(q_in, k_in, Wqb, Wkb, bq, bk, pqT, pkT);
    proj_v_k<<<dim3(256, 4), 256, 0, stream>>>(v_in, Wvb, bv, pvb);
    attn_split_k<<<dim3(64, KS, 4), 256, 0, stream>>>(pqT, pkT, pvb, accP, lP, KS);
    combine_k<<<4096, 256, 0, stream>>>(accP, lP, v_in, gamma, out, KS);
}

// Round 10
// 99.755 us; speedup vs baseline: 1.3046x; 1.3046x over previous
//
#include <hip/hip_runtime.h>
#include <hip/hip_bf16.h>

typedef __attribute__((ext_vector_type(8))) short short8_t;
typedef __attribute__((ext_vector_type(4))) short short4_t;
typedef __attribute__((ext_vector_type(4))) float float4_t;

#define B_   4
#define C_   256
#define N_   4096
#define DQK  32
#define LOG2E 1.4426950408889634f

#define VMCNT12  asm volatile("s_waitcnt vmcnt(12)" ::: "memory")
#define VMCNT4   asm volatile("s_waitcnt vmcnt(4)" ::: "memory")
#define LGKM0    asm volatile("s_waitcnt lgkmcnt(0)" ::: "memory")
#define SBAR     __builtin_amdgcn_s_barrier()
#define SCHEDB   __builtin_amdgcn_sched_barrier(0)

__device__ __forceinline__ unsigned short f2bf(float x) {
    union { float f; unsigned int u; } v; v.f = x;
    unsigned int r = v.u + 0x7FFFu + ((v.u >> 16) & 1u);   // RNE
    return (unsigned short)(r >> 16);
}
__device__ __forceinline__ unsigned short f2bf_hw(float x) {
    return __bfloat16_as_ushort(__float2bfloat16(x));      // hw RNE, pairs to cvt_pk
}

// ---------------- weight casts ----------------
__global__ __launch_bounds__(256) void cast_w_k(
        const float* __restrict__ Wq, const float* __restrict__ Wk,
        const float* __restrict__ Wv,
        unsigned short* __restrict__ Wqb, unsigned short* __restrict__ Wkb,
        unsigned short* __restrict__ Wvb) {
    int i = blockIdx.x * 256 + threadIdx.x;
    if (i < 8192)            Wqb[i] = f2bf(Wq[i]);
    else if (i < 16384)      Wkb[i - 8192] = f2bf(Wk[i - 8192]);
    else                     Wvb[i - 16384] = f2bf(Wv[i - 16384]);
}

// ---------------- pq / pk projection, reading x f32 [b][c][n] directly ----------------
__global__ __launch_bounds__(256) void proj_qk_k(
        const float* __restrict__ q_in, const float* __restrict__ k_in,
        const unsigned short* __restrict__ Wqb, const unsigned short* __restrict__ Wkb,
        const float* __restrict__ bq, const float* __restrict__ bk,
        unsigned short* __restrict__ pqT, unsigned short* __restrict__ pkT) {
    int b = blockIdx.y, z = blockIdx.z;
    const float* X = z ? k_in : q_in;
    const unsigned short* W = z ? Wkb : Wqb;
    const float* bias = z ? bk : bq;
    unsigned short* P = z ? pkT : pqT;
    float scl = z ? 1.0f : LOG2E;
    int tid = threadIdx.x, wave = tid >> 6, lane = tid & 63, l15 = lane & 15, g = lane >> 4;
    int nb = blockIdx.x * 64 + wave * 16;
    float4_t acc0 = {0.f, 0.f, 0.f, 0.f}, acc1 = {0.f, 0.f, 0.f, 0.f};
    const float* Xcol = X + (size_t)b * C_ * N_ + nb + l15;
#pragma unroll
    for (int kk = 0; kk < 8; ++kk) {
        short8_t a;
#pragma unroll
        for (int j = 0; j < 8; ++j)
            a[j] = (short)f2bf(Xcol[(size_t)(kk * 32 + 8 * g + j) * N_]);
        short8_t b0 = *(const short8_t*)(W + (size_t)l15 * C_ + kk * 32 + 8 * g);
        short8_t b1 = *(const short8_t*)(W + (size_t)(16 + l15) * C_ + kk * 32 + 8 * g);
        acc0 = __builtin_amdgcn_mfma_f32_16x16x32_bf16(a, b0, acc0, 0, 0, 0);
        acc1 = __builtin_amdgcn_mfma_f32_16x16x32_bf16(a, b1, acc1, 0, 0, 0);
    }
#pragma unroll
    for (int r = 0; r < 4; ++r) {
        int n = nb + 4 * g + r;
        P[((size_t)b * N_ + n) * DQK + l15]      = f2bf((acc0[r] + bias[l15]) * scl);
        P[((size_t)b * N_ + n) * DQK + 16 + l15] = f2bf((acc1[r] + bias[16 + l15]) * scl);
    }
}

// ---------------- pv projection: pv[b][c][m'] = Wv x v + bv, keys pi-permuted ----------------
__global__ __launch_bounds__(256) void proj_v_k(
        const float* __restrict__ v_in, const unsigned short* __restrict__ Wvb,
        const float* __restrict__ bv, unsigned short* __restrict__ pv) {
    int b = blockIdx.y;
    int tid = threadIdx.x, wave = tid >> 6, lane = tid & 63, l15 = lane & 15, g = lane >> 4;
    int mb = blockIdx.x * 16;
    int m = mb + l15;
    int k32 = m & 31;
    int pcol = (k32 < 16) ? ((k32 >> 2) * 8 + (k32 & 3))
                          : (((k32 - 16) >> 2) * 8 + 4 + (k32 & 3));
    int mcol = (m & ~31) + pcol;
    float4_t acc[4];
#pragma unroll
    for (int i = 0; i < 4; ++i) acc[i] = (float4_t){0.f, 0.f, 0.f, 0.f};
    const float* Vcol = v_in + (size_t)b * C_ * N_ + mb + l15;
#pragma unroll
    for (int kk = 0; kk < 8; ++kk) {
        short8_t bf;
#pragma unroll
        for (int j = 0; j < 8; ++j)
            bf[j] = (short)f2bf(Vcol[(size_t)(kk * 32 + 8 * g + j) * N_]);
#pragma unroll
        for (int ct = 0; ct < 4; ++ct) {
            short8_t af = *(const short8_t*)(Wvb + (size_t)(wave * 64 + ct * 16 + l15) * C_ + kk * 32 + 8 * g);
            acc[ct] = __builtin_amdgcn_mfma_f32_16x16x32_bf16(af, bf, acc[ct], 0, 0, 0);
        }
    }
#pragma unroll
    for (int ct = 0; ct < 4; ++ct)
#pragma unroll
        for (int r = 0; r < 4; ++r) {
            int c = wave * 64 + ct * 16 + 4 * g + r;
            pv[((size_t)b * C_ + c) * N_ + mcol] = f2bf(acc[ct][r] + bv[c]);
        }
}

// ---------------- flash attention: wave-private V via async LDS, P through LDS ----------------
// Wave w: produces P for q-slice w (16q); consumes PV for channels [64w,64w+64)
// x all 64q. V staged global->LDS with global_load_lds (fire-and-forget, counted
// vmcnt) into wave-OWN rows; read back swizzled b128 -- fully wave-private, no
// barrier needed for V. P(t+1) produced during tile t, shared via 2x8KB LDS
// ping-pong; ONE barrier per tile (P visibility only). l via ones-row MFMA.
__global__ __launch_bounds__(256, 2) void attn_split_k(
        const unsigned short* __restrict__ pqT, const unsigned short* __restrict__ pkT,
        const unsigned short* __restrict__ pv,
        float* __restrict__ accP, float* __restrict__ lP, int KS) {
    __shared__ __align__(16) unsigned short VT[2][256][64];   // 64KB
    __shared__ __align__(16) short8_t Pl[2][4][2][4][16];     // 16KB [buf][qt][kh][g][l15]
    // XCD-chunked bijective swizzle: each XCD covers all 64 qb of one (s,b)
    int nqb = gridDim.x;
    int lin = blockIdx.x + nqb * (blockIdx.y + KS * blockIdx.z);
    int cpx = (nqb * KS * 4) >> 3;
    int sl  = (lin & 7) * cpx + (lin >> 3);
    int qbi = sl % nqb;
    int s   = (sl / nqb) % KS;
    int b   = sl / (nqb * KS);

    int kps = N_ / KS, ks0 = s * kps, nt = kps >> 6;
    int tid = threadIdx.x, wave = tid >> 6, lane = tid & 63, l15 = lane & 15, g = lane >> 4;
    int qb = qbi * 64;
    int sw = (l15 & 7) << 4;
    int rl = lane >> 3, cl = (lane & 7) ^ rl;                 // staging source permute

    short8_t qf = *(const short8_t*)(pqT + ((size_t)b * N_ + qb + wave * 16 + l15) * DQK + 8 * g);
    float4_t acc[4][4];   // [ct][qt]
#pragma unroll
    for (int i = 0; i < 4; ++i)
#pragma unroll
        for (int j = 0; j < 4; ++j) acc[i][j] = (float4_t){0.f, 0.f, 0.f, 0.f};
    float4_t accl = {0.f, 0.f, 0.f, 0.f};
    short8_t onef;
#pragma unroll
    for (int j = 0; j < 8; ++j) onef[j] = (short)0x3F80;      // bf16 1.0
    const float4_t zero4 = {0.f, 0.f, 0.f, 0.f};
    const char* pvb8 = (const char*)(pv + (size_t)b * C_ * N_);
    const char* pkTb = (const char*)pkT + (size_t)b * N_ * DQK * 2;

    // persistent byte offsets
    unsigned soff[8];
#pragma unroll
    for (int i = 0; i < 8; ++i)
        soff[i] = (unsigned)(((wave * 64 + i * 8 + rl) * N_ + ks0 + 8 * cl) * 2);
    unsigned koff = (unsigned)(((ks0 + l15) * DQK + 8 * g) * 2);
    // V-read bases: rows wave*64 + ct*16 + l15, XOR-swizzled; imm = RB*32768 + ct*2048
    const char* vbA = (const char*)&VT[0][0][0] + (wave * 64 + l15) * 128 + ((16 * g) ^ sw);
    const char* vbB = (const char*)&VT[0][0][0] + (wave * 64 + l15) * 128 + ((64 + 16 * g) ^ sw);

#define STAGE(RBUF)                                                           \
    _Pragma("unroll")                                                         \
    for (int i_ = 0; i_ < 8; ++i_) {                                          \
        __builtin_amdgcn_global_load_lds(                                     \
            (const __attribute__((address_space(1))) unsigned int*)(const void*)(pvb8 + soff[i_]), \
            (__attribute__((address_space(3))) unsigned int*)(void*)&VT[RBUF][wave * 64 + i_ * 8][0], 16, 0, 0); \
        soff[i_] += 128;                                                      \
    }

#define KFLOAD(DST)                                                           \
    _Pragma("unroll")                                                         \
    for (int it_ = 0; it_ < 4; ++it_)                                         \
        DST[it_] = *(const short8_t*)(pkTb + koff + it_ * 1024);              \
    koff += 4096;

#define VREAD(DST, RB)                                                        \
    _Pragma("unroll")                                                         \
    for (int ct_ = 0; ct_ < 4; ++ct_) {                                       \
        DST[ct_][0] = *(const short8_t*)(vbA + (RB) * 32768 + ct_ * 2048);    \
        DST[ct_][1] = *(const short8_t*)(vbB + (RB) * 32768 + ct_ * 2048);    \
    }

#define PFREAD(DST, CB)                                                       \
    _Pragma("unroll")                                                         \
    for (int qt_ = 0; qt_ < 4; ++qt_)                                         \
        _Pragma("unroll")                                                     \
        for (int kh_ = 0; kh_ < 2; ++kh_)                                     \
            DST[qt_][kh_] = Pl[CB][qt_][kh_][g][l15];

// QK(t+1) -> exp2 -> pack -> accl -> ds_write to Pl[NB]
#define QKWR(KF, NB)                                                          \
    {                                                                          \
        float4_t sv_[4];                                                       \
        _Pragma("unroll")                                                      \
        for (int it_ = 0; it_ < 4; ++it_)                                      \
            sv_[it_] = __builtin_amdgcn_mfma_f32_16x16x32_bf16(KF[it_], qf, zero4, 0, 0, 0); \
        float p_[16];                                                          \
        _Pragma("unroll")                                                      \
        for (int it_ = 0; it_ < 4; ++it_)                                      \
            _Pragma("unroll")                                                  \
            for (int r_ = 0; r_ < 4; ++r_)                                     \
                p_[it_ * 4 + r_] = exp2f(sv_[it_][r_]);                        \
        short8_t pbn0_, pbn1_;                                                 \
        _Pragma("unroll")                                                      \
        for (int j_ = 0; j_ < 4; ++j_) {                                       \
            pbn0_[j_]     = (short)f2bf_hw(p_[j_]);                            \
            pbn0_[4 + j_] = (short)f2bf_hw(p_[4 + j_]);                        \
            pbn1_[j_]     = (short)f2bf_hw(p_[8 + j_]);                        \
            pbn1_[4 + j_] = (short)f2bf_hw(p_[12 + j_]);                       \
        }                                                                      \
        accl = __builtin_amdgcn_mfma_f32_16x16x32_bf16(onef, pbn0_, accl, 0, 0, 0); \
        accl = __builtin_amdgcn_mfma_f32_16x16x32_bf16(onef, pbn1_, accl, 0, 0, 0); \
        Pl[NB][wave][0][g][l15] = pbn0_;                                       \
        Pl[NB][wave][1][g][l15] = pbn1_;                                       \
    }

#define PVM_ALL(VF, PF)                                                       \
    _Pragma("unroll")                                                         \
    for (int ct_ = 0; ct_ < 4; ++ct_)                                         \
        _Pragma("unroll")                                                     \
        for (int qt_ = 0; qt_ < 4; ++qt_) {                                   \
            acc[ct_][qt_] = __builtin_amdgcn_mfma_f32_16x16x32_bf16(VF[ct_][0], PF[qt_][0], acc[ct_][qt_], 0, 0, 0); \
            acc[ct_][qt_] = __builtin_amdgcn_mfma_f32_16x16x32_bf16(VF[ct_][1], PF[qt_][1], acc[ct_][qt_], 0, 0, 0); \
        }

// body(T): stage V(T+1); drain own V(T) staging; read V(T)+P(T); produce P(T+1);
// PV(T); one barrier (P visibility).
#define BODY(T, RB, KFC, CB, NB)                                              \
    {                                                                          \
        if ((T) + 1 < nt) { STAGE((RB) ^ 1) VMCNT12; } else { VMCNT4; }        \
        SCHEDB;                                                                \
        short8_t vf_[4][2], pf_[4][2];                                         \
        VREAD(vf_, RB)                                                         \
        PFREAD(pf_, CB)                                                        \
        if ((T) + 1 < nt) { QKWR(KFC, NB) }                                    \
        KFLOAD(KFC)                                                            \
        __builtin_amdgcn_s_setprio(1);                                         \
        PVM_ALL(vf_, pf_)                                                      \
        __builtin_amdgcn_s_setprio(0);                                         \
        LGKM0; SCHEDB;                                                         \
        SBAR;                                                                  \
    }

    // ---- prologue ----
    short8_t kfA[4], kfB[4];
    STAGE(0)             // V(0)
    KFLOAD(kfA)          // kf(0)
    KFLOAD(kfB)          // kf(1)
    QKWR(kfA, 0)         // P(0) -> buf0 (vmcnt wait here also drains STAGE)
    KFLOAD(kfA)          // kf(2)
    LGKM0; SCHEDB;
    SBAR;

    for (int t = 0; t < nt; t += 2) {
        BODY(t,     0, kfB, 0, 1)
        BODY(t + 1, 1, kfA, 1, 0)
    }

    // ---- epilogue: partial acc + l ----
    if (g == 0)
        lP[(size_t)(b * KS + s) * N_ + qb + wave * 16 + l15] = accl[0];
    float* accOut = accP + ((size_t)(b * KS + s) * C_) * N_;
#pragma unroll
    for (int ct = 0; ct < 4; ++ct)
#pragma unroll
        for (int qt = 0; qt < 4; ++qt)
#pragma unroll
            for (int r = 0; r < 4; ++r) {
                int c = wave * 64 + ct * 16 + 4 * g + r;
                accOut[(size_t)c * N_ + qb + qt * 16 + l15] = acc[ct][qt][r];
            }
#undef STAGE
#undef KFLOAD
#undef VREAD
#undef PFREAD
#undef QKWR
#undef PVM_ALL
#undef BODY
}

// ---------------- combine splits + normalize + gamma*out + v ----------------
__global__ __launch_bounds__(256) void combine_k(
        const float* __restrict__ accP, const float* __restrict__ lP,
        const float* __restrict__ v_in, const float* __restrict__ gamma,
        float* __restrict__ out, int KS) {
    int i = blockIdx.x * 256 + threadIdx.x;
    const int nq4 = N_ / 4;
    int q0 = (i % nq4) * 4;
    int c  = (i / nq4) % C_;
    int b  = i / (nq4 * C_);
    float4_t num = {0.f, 0.f, 0.f, 0.f}, den = {0.f, 0.f, 0.f, 0.f};
    for (int s = 0; s < KS; ++s) {
        float4_t l4 = *(const float4_t*)(lP + (size_t)(b * KS + s) * N_ + q0);
        float4_t a4 = *(const float4_t*)(accP + ((size_t)(b * KS + s) * C_ + c) * N_ + q0);
#pragma unroll
        for (int j = 0; j < 4; ++j) {
            den[j] += l4[j];
            num[j] += a4[j];
        }
    }
    float gm = gamma[0];
    size_t idx = ((size_t)(b * C_ + c)) * N_ + q0;
    float4_t vi = *(const float4_t*)(v_in + idx);
    float4_t o;
#pragma unroll
    for (int j = 0; j < 4; ++j) o[j] = gm * num[j] / den[j] + vi[j];
    *(float4_t*)(out + idx) = o;
}

extern "C" void kernel_launch(void* const* d_in, const int* in_sizes, int n_in,
                              void* d_out, int out_size, void* d_ws, size_t ws_size,
                              hipStream_t stream) {
    (void)in_sizes; (void)n_in; (void)out_size;
    const float* v_in  = (const float*)d_in[0];
    const float* k_in  = (const float*)d_in[1];
    const float* q_in  = (const float*)d_in[2];
    const float* Wq    = (const float*)d_in[3];
    const float* bq    = (const float*)d_in[4];
    const float* Wk    = (const float*)d_in[5];
    const float* bk    = (const float*)d_in[6];
    const float* Wv    = (const float*)d_in[7];
    const float* bv    = (const float*)d_in[8];
    const float* gamma = (const float*)d_in[9];
    float* out = (float*)d_out;

    char* ws = (char*)d_ws;
    unsigned short* pvb = (unsigned short*)(ws + 0);          // 8.39 MB [b][c][m'] pi-permuted
    unsigned short* pqT = (unsigned short*)(ws + 8388608);    // 1 MB [b][n][32] (x log2e)
    unsigned short* pkT = (unsigned short*)(ws + 9437184);    // 1 MB + 24 KB pad (pipelined overread)
    unsigned short* Wqb = (unsigned short*)(ws + 10502144);   // 16 KB
    unsigned short* Wkb = (unsigned short*)(ws + 10518528);   // 16 KB
    unsigned short* Wvb = (unsigned short*)(ws + 10534912);   // 128 KB
    const size_t base2 = 10665984;

    int KS = 2;
    while (KS > 1) {
        size_t need = base2 + (size_t)KS * 16777216 + (size_t)KS * 262144;
        if (need <= ws_size) break;
        KS >>= 1;
    }
    float* accP = (float*)(ws + base2);                          // KS*16.78 MB [b][s][c][q]
    float* lP   = (float*)(ws + base2 + (size_t)KS * 16777216);  // KS*64 KB

    cast_w_k<<<320, 256, 0, stream>>>(Wq, Wk, Wv, Wqb, Wkb, Wvb);
    proj_qk_k<<<dim3(64, 4, 2), 256, 0, stream>>>(q_in, k_in, Wqb, Wkb, bq, bk, pqT, pkT);
    proj_v_k<<<dim3(256, 4), 256, 0, stream>>>(v_in, Wvb, bv, pvb);
    attn_split_k<<<dim3(64, KS, 4), 256, 0, stream>>>(pqT, pkT, pvb, accP, lP, KS);
    combine_k<<<4096, 256, 0, stream>>>(accP, lP, v_in, gamma, out, KS);
}